// Round 26
// baseline (490.035 us; speedup 1.0000x reference)
//
#include <hip/hip_runtime.h>
#include <hip/hip_bf16.h>

#define DD 256      // feature dim
#define NM 64       // memory slots

typedef unsigned long long u64;
typedef float v2f __attribute__((ext_vector_type(2)));

struct v2x2 { v2f lo, hi; };
static __device__ __forceinline__ v2x2 splitf4(float4 f) {
    union { float4 a; v2x2 b; } u; u.a = f; return u.b;
}

// pk: acc(pair) += splat(src0 half) * c(pair).  Bit-identical to two fmaf.
#define PK_FMA_SPLATLO(acc, q2, c2) \
    asm("v_pk_fma_f32 %0, %1, %2, %0 op_sel:[0,0,0] op_sel_hi:[0,1,1]" \
        : "+v"(acc) : "v"(q2), "v"(c2))
#define PK_FMA_SPLATHI(acc, q2, c2) \
    asm("v_pk_fma_f32 %0, %1, %2, %0 op_sel:[1,0,0] op_sel_hi:[1,1,1]" \
        : "+v"(acc) : "v"(q2), "v"(c2))

// ---------------------------------------------------------------------------
// prep_tr: wt[d][o] = W[o][d] for Wq and Wk
// ---------------------------------------------------------------------------
__global__ __launch_bounds__(256) void prep_tr(
    const float* __restrict__ Wq, const float* __restrict__ Wk,
    float* __restrict__ wqt, float* __restrict__ wkt)
{
    const int o = blockIdx.x;
    const int d = threadIdx.x;
    if (blockIdx.y == 0) wqt[d * DD + o] = Wq[o * DD + d];
    else                 wkt[d * DD + o] = Wk[o * DD + d];
}

// ---------------------------------------------------------------------------
// prep_kT: kT4[(o>>2)*(NM*4) + n*4 + (o&3)] = k[n][o]   ([og][n][4] layout)
//   k[n][o] = sum_d mem[n][d]*Wk[o][d]  (fp32, d-ascending single-acc)
//   bias[n] = fl32(max(log(imp*0.99^age), -10))
// ---------------------------------------------------------------------------
__global__ __launch_bounds__(256) void prep_kT(
    const float* __restrict__ mem, const float* __restrict__ wkt,
    const float* __restrict__ imp, const float* __restrict__ age,
    float* __restrict__ kT4, float* __restrict__ bias)
{
    const int n = blockIdx.x;
    const int o = threadIdx.x;
    const float* mrow = mem + n * DD;
    float acc = 0.f;
    for (int d = 0; d < DD; ++d)
        acc = fmaf(mrow[d], wkt[d * DD + o], acc);
    kT4[(o >> 2) * (NM * 4) + n * 4 + (o & 3)] = acc;

    if (o == 0) {
        double eff = (double)imp[n] * pow(0.99, (double)age[n]);
        float b = (float)log(eff);
        if (!(b >= -10.0f)) b = -10.0f;
        bias[n] = b;
    }
}

// ---------------------------------------------------------------------------
// qgemm5: q = query @ Wq^T -> qout. Byte-identical to R25 (221 us; accepted
// basin — 8 structural variants all 220-242 us, invariant ~90 us stall over
// the 109 us fp32-FMA floor = the barrier/waitcnt drain HIP can't remove).
// ---------------------------------------------------------------------------
__global__ __launch_bounds__(256, 2) void qgemm5(
    const float* __restrict__ query,   // [M][DD]
    const float4* __restrict__ wqt4,   // [DD][NM]: wqt4[d*64+l] = WqT[d][4l..4l+3]
    float* __restrict__ qout,          // [M][DD]
    int M)
{
    __shared__ float wq_lds[2][8 * 256];    // 16 KB dbuf: [d_local][o]
    __shared__ float qc_lds[2][64 * 8];     // 4 KB dbuf: [row][d_local]

    const int t = threadIdx.x;              // 0..255
    const int l = t & 63;
    const int w = __builtin_amdgcn_readfirstlane((int)(t >> 6));  // 0..3
    const int row0 = blockIdx.x * 64;

    const int sr = t >> 2;                  // 0..63
    const int sd = (t & 3) * 2;             // 0,2,4,6
    int srow = row0 + sr; if (srow > M - 1) srow = M - 1;
    const float* qsrc = query + (size_t)srow * DD + sd;

    // stage chunk 0
    {
        const float2 qv = *reinterpret_cast<const float2*>(qsrc);
        *reinterpret_cast<float2*>(&qc_lds[0][sr * 8 + sd]) = qv;
        const float4 s0 = wqt4[t];
        const float4 s1 = wqt4[256 + t];
        reinterpret_cast<float4*>(wq_lds[0])[t]       = s0;
        reinterpret_cast<float4*>(wq_lds[0])[256 + t] = s1;
    }
    __syncthreads();

    v2f a01[16], a23[16];
#pragma unroll
    for (int rr = 0; rr < 16; ++rr) { a01[rr] = (v2f)(0.f); a23[rr] = (v2f)(0.f); }

    for (int c = 0; c < 32; ++c) {
        const int cn = (c + 1) & 31;
        const float2 nq = *reinterpret_cast<const float2*>(qsrc + cn * 8);
        const float4 n0 = wqt4[cn * 512 + t];
        const float4 n1 = wqt4[cn * 512 + 256 + t];

        {
            const float4* wb = reinterpret_cast<const float4*>(wq_lds[c & 1]);
            float4 cw[8];
#pragma unroll
            for (int i = 0; i < 8; ++i) cw[i] = wb[i * 64 + l];
            const v2x2 c0 = splitf4(cw[0]), c1 = splitf4(cw[1]);
            const v2x2 c2 = splitf4(cw[2]), c3 = splitf4(cw[3]);
            const v2x2 c4 = splitf4(cw[4]), c5 = splitf4(cw[5]);
            const v2x2 c6 = splitf4(cw[6]), c7 = splitf4(cw[7]);
            const float* qcb = &qc_lds[c & 1][(w * 16) * 8];
#pragma unroll
            for (int rr = 0; rr < 16; ++rr) {
                const float4 qqA = *reinterpret_cast<const float4*>(qcb + rr * 8);
                const float4 qqB = *reinterpret_cast<const float4*>(qcb + rr * 8 + 4);
                const v2x2 qA = splitf4(qqA);
                const v2x2 qB = splitf4(qqB);
                // d-ascending per chain (bit-identical):
                PK_FMA_SPLATLO(a01[rr], qA.lo, c0.lo);
                PK_FMA_SPLATLO(a23[rr], qA.lo, c0.hi);
                PK_FMA_SPLATHI(a01[rr], qA.lo, c1.lo);
                PK_FMA_SPLATHI(a23[rr], qA.lo, c1.hi);
                PK_FMA_SPLATLO(a01[rr], qA.hi, c2.lo);
                PK_FMA_SPLATLO(a23[rr], qA.hi, c2.hi);
                PK_FMA_SPLATHI(a01[rr], qA.hi, c3.lo);
                PK_FMA_SPLATHI(a23[rr], qA.hi, c3.hi);
                PK_FMA_SPLATLO(a01[rr], qB.lo, c4.lo);
                PK_FMA_SPLATLO(a23[rr], qB.lo, c4.hi);
                PK_FMA_SPLATHI(a01[rr], qB.lo, c5.lo);
                PK_FMA_SPLATHI(a23[rr], qB.lo, c5.hi);
                PK_FMA_SPLATLO(a01[rr], qB.hi, c6.lo);
                PK_FMA_SPLATLO(a23[rr], qB.hi, c6.hi);
                PK_FMA_SPLATHI(a01[rr], qB.hi, c7.lo);
                PK_FMA_SPLATHI(a23[rr], qB.hi, c7.hi);
            }
        }
        {
            *reinterpret_cast<float2*>(&qc_lds[(c + 1) & 1][sr * 8 + sd]) = nq;
            float4* dst = reinterpret_cast<float4*>(wq_lds[(c + 1) & 1]);
            dst[t]       = n0;
            dst[256 + t] = n1;
        }
        __syncthreads();
    }

#pragma unroll
    for (int rr = 0; rr < 16; ++rr) {
        const int grow = row0 + w * 16 + rr;
        if (grow < M) {
            float4 v; v.x = a01[rr].x; v.y = a01[rr].y; v.z = a23[rr].x; v.w = a23[rr].y;
            *reinterpret_cast<float4*>(&qout[(size_t)grow * DD + 4 * l]) = v;
        }
    }
}

// ---------------------------------------------------------------------------
// sfin2: scores + topk + attn + PV in ONE kernel (eliminates the 66 MB
// score HBM roundtrip + one launch + one staging pass of R25's tail).
// NOT R20's failed sfin (lane=n scores, 45KB/21% occ): keeps scores_b's
// proven lane=row + s_load-kT loop and 512-thr/64-row shape; after the tile
// write, fin3's exact topk (thread-per-row) + attn stores + rank-ascending
// PV (8 rows/wave). All chains bit-identical to R25's passing code.
// Block-local RAW: stages q rows from out_ret, later overwrites them.
// ---------------------------------------------------------------------------
__global__ __launch_bounds__(512, 2) void sfin2(
    const float* __restrict__ qin,     // [M][DD] (= out_ret)
    const float* __restrict__ mem,     // [NM][DD]
    const float4* __restrict__ kT44,   // [DD/4][NM]
    const float* __restrict__ bias,    // [NM]
    const int* __restrict__ topk_p,
    float* __restrict__ out_ret,       // [M][DD] (same buffer as qin)
    float* __restrict__ out_attn,      // [M][NM]
    int M)
{
    __shared__ float q_lds[64 * DD];   // 64 KB; aliased after q reads:
    float* s_tmp = q_lds;              //   [64][64] rotated scores = 16 KB
    int*   sel_i = (int*)(q_lds + 64 * NM);          // [64][16] = 4 KB
    float* sel_w = q_lds + 64 * NM + 64 * 16;        // [64][16] = 4 KB

    const int t = threadIdx.x;         // 0..511
    const int l = t & 63;
    const int w = __builtin_amdgcn_readfirstlane((int)(t >> 6));  // 0..7
    const int row0 = blockIdx.x * 64;
    const int k = *topk_p;

    // ---- stage 64 q rows (coalesced read; swizzled write: f4-col c4 -> c4^r)
    {
        const float4* q4g = reinterpret_cast<const float4*>(qin);
#pragma unroll
        for (int i = 0; i < 8; ++i) {
            const int idx = i * 512 + t;
            const int r = idx >> 6, c4 = idx & 63;
            int gr = row0 + r; if (gr > M - 1) gr = M - 1;
            *reinterpret_cast<float4*>(&q_lds[r * DD + ((c4 ^ r) & 63) * 4]) =
                q4g[(size_t)gr * 64 + c4];
        }
    }
    __syncthreads();

    // ---- scores: lane l = row l; wave w owns n in [8w, 8w+8)  (== scores_b)
    const int nb = w * 8;
    float sc[8];
#pragma unroll
    for (int j = 0; j < 8; ++j) sc[j] = 0.f;

    for (int og = 0; og < DD / 4; ++og) {
        const float4 q4 = *reinterpret_cast<const float4*>(
            &q_lds[l * DD + (((og ^ l) & 63) << 2)]);     // per-lane, conflict-free
        const float4* ktp = kT44 + og * NM + nb;          // wave-uniform -> s_load
#pragma unroll
        for (int j = 0; j < 8; ++j) {
            const float4 kt = ktp[j];
            float v = sc[j];
            v = fmaf(q4.x, kt.x, v);                      // o-ascending chain
            v = fmaf(q4.y, kt.y, v);
            v = fmaf(q4.z, kt.z, v);
            v = fmaf(q4.w, kt.w, v);
            sc[j] = v;
        }
    }
    __syncthreads();   // all q reads done -> LDS reusable for scores/sel

    // ---- rotated score tile: row l, col c stored at (c+l)&63
#pragma unroll
    for (int j = 0; j < 8; ++j)
        s_tmp[l * NM + ((nb + j + l) & 63)] = sc[j] * 0.0625f + bias[nb + j];
    __syncthreads();

    // ---- per-row top-k: thread t handles row t (t < 64)  (== fin3)
    if (t < 64) {
        const int r = t;
        float sv[NM];
#pragma unroll
        for (int n = 0; n < NM; ++n) sv[n] = s_tmp[r * NM + ((n + r) & 63)];

        if (k < NM) {
            const int kk = k < 16 ? k : 16;   // dataset: k = 8
            u64 taken = 0ull;
            float mmax = 0.f, Z = 0.f;
            for (int i = 0; i < kk; ++i) {
                float m = -1.0e30f;
                int idx = 0;
#pragma unroll
                for (int n = 0; n < NM; ++n) {
                    const bool avail  = ((taken >> n) & 1ull) == 0ull;
                    const bool better = avail && (sv[n] > m);  // strict >: lowest idx ties
                    m   = better ? sv[n] : m;
                    idx = better ? n : idx;
                }
                taken |= (1ull << idx);
                if (i == 0) mmax = m;
                const float wv = expf(m - mmax);
                Z += wv;
                sel_i[r * 16 + i] = idx;
                sel_w[r * 16 + i] = wv;
            }
#pragma unroll
            for (int n = 0; n < NM; ++n) s_tmp[r * NM + ((n + r) & 63)] = 0.f;
            for (int i = 0; i < kk; ++i) {
                const float wz = sel_w[r * 16 + i] / Z;
                sel_w[r * 16 + i] = wz;
                s_tmp[r * NM + ((sel_i[r * 16 + i] + r) & 63)] = wz;
            }
        } else {
            float m = -1.0e30f;
#pragma unroll
            for (int n = 0; n < NM; ++n) m = sv[n] > m ? sv[n] : m;
            float Z = 0.f;
#pragma unroll
            for (int n = 0; n < NM; ++n) Z += expf(sv[n] - m);
#pragma unroll
            for (int n = 0; n < NM; ++n) s_tmp[r * NM + ((n + r) & 63)] = expf(sv[n] - m) / Z;
        }
    }
    __syncthreads();

    // ---- attn stores (coalesced)
#pragma unroll
    for (int i = 0; i < 8; ++i) {
        const int idx = i * 512 + t;
        const int r = idx >> 6, n = idx & 63;
        const int grow = row0 + r;
        if (grow < M) out_attn[(size_t)grow * NM + n] = s_tmp[r * NM + ((n + r) & 63)];
    }

    // ---- retrieved (PV): wave w rows [8w, 8w+8); lane l = d-quad
    {
        const float4* mem4 = reinterpret_cast<const float4*>(mem);   // [NM][64]
        const int kk = k < 16 ? k : 16;
#pragma unroll 1
        for (int rr = 0; rr < 8; ++rr) {
            const int r    = w * 8 + rr;
            const int grow = row0 + r;
            if (grow >= M) continue;
            float4 acc; acc.x = 0.f; acc.y = 0.f; acc.z = 0.f; acc.w = 0.f;
            if (k < NM) {
                for (int i = 0; i < kk; ++i) {
                    const int   mi = sel_i[r * 16 + i];      // uniform ds
                    const float wz = sel_w[r * 16 + i];
                    const float4 mv = mem4[mi * 64 + l];     // coalesced, L1-hot
                    acc.x = fmaf(wz, mv.x, acc.x);           // rank-ascending chain
                    acc.y = fmaf(wz, mv.y, acc.y);
                    acc.z = fmaf(wz, mv.z, acc.z);
                    acc.w = fmaf(wz, mv.w, acc.w);
                }
            } else {
                for (int n = 0; n < NM; ++n) {
                    const float wz = s_tmp[r * NM + ((n + r) & 63)];
                    const float4 mv = mem4[n * 64 + l];
                    acc.x = fmaf(wz, mv.x, acc.x);           // n-ascending chain
                    acc.y = fmaf(wz, mv.y, acc.y);
                    acc.z = fmaf(wz, mv.z, acc.z);
                    acc.w = fmaf(wz, mv.w, acc.w);
                }
            }
            *reinterpret_cast<float4*>(&out_ret[(size_t)grow * DD + 4 * l]) = acc;
        }
    }
}

// ---------------------------------------------------------------------------
extern "C" void kernel_launch(void* const* d_in, const int* in_sizes, int n_in,
                              void* d_out, int out_size, void* d_ws, size_t ws_size,
                              hipStream_t stream) {
    const float* query      = (const float*)d_in[0];
    const float* memory     = (const float*)d_in[1];
    const float* importance = (const float*)d_in[2];
    const float* age        = (const float*)d_in[3];
    const float* Wq         = (const float*)d_in[4];
    const float* Wk         = (const float*)d_in[5];
    const int*   topk       = (const int*)d_in[6];

    const int M = in_sizes[0] / DD;   // B*S = 131072

    float* kT4  = (float*)d_ws;                      // 64 KB [og][n][4]
    float* bias = kT4 + (size_t)DD * NM;             // [NM]
    float* wqt  = bias + 64;                         // [DD][DD] = 256 KB
    float* wkt  = wqt + (size_t)DD * DD;             // [DD][DD] = 256 KB

    hipLaunchKernelGGL(prep_tr, dim3(DD, 2), dim3(DD), 0, stream,
                       Wq, Wk, wqt, wkt);
    hipLaunchKernelGGL(prep_kT, dim3(NM), dim3(DD), 0, stream,
                       memory, wkt, importance, age, kT4, bias);

    float* out_ret  = (float*)d_out;
    float* out_attn = out_ret + (size_t)M * DD;

    // q staged through out_ret; sfin2 reads its own rows before overwriting
    // them with retrieved, and writes attn directly (no score roundtrip).
    hipLaunchKernelGGL(qgemm5, dim3((M + 63) / 64), dim3(256), 0, stream,
                       query, (const float4*)wqt, out_ret, M);
    hipLaunchKernelGGL(sfin2, dim3((M + 63) / 64), dim3(512), 0, stream,
                       out_ret, memory, (const float4*)kT4, bias, topk,
                       out_ret, out_attn, M);
}

// Round 27
// 384.365 us; speedup vs baseline: 1.2749x; 1.2749x over previous
//
#include <hip/hip_runtime.h>
#include <hip/hip_bf16.h>

#define DD 256      // feature dim
#define NM 64       // memory slots

typedef unsigned long long u64;
typedef float v2f __attribute__((ext_vector_type(2)));

struct v2x2 { v2f lo, hi; };
static __device__ __forceinline__ v2x2 splitf4(float4 f) {
    union { float4 a; v2x2 b; } u; u.a = f; return u.b;
}

// pk: acc(pair) += splat(src0 half) * c(pair).  Bit-identical to two fmaf.
#define PK_FMA_SPLATLO(acc, q2, c2) \
    asm("v_pk_fma_f32 %0, %1, %2, %0 op_sel:[0,0,0] op_sel_hi:[0,1,1]" \
        : "+v"(acc) : "v"(q2), "v"(c2))
#define PK_FMA_SPLATHI(acc, q2, c2) \
    asm("v_pk_fma_f32 %0, %1, %2, %0 op_sel:[1,0,0] op_sel_hi:[1,1,1]" \
        : "+v"(acc) : "v"(q2), "v"(c2))

// ---------------------------------------------------------------------------
// prep_tr: wt[d][o] = W[o][d] for Wq and Wk
// ---------------------------------------------------------------------------
__global__ __launch_bounds__(256) void prep_tr(
    const float* __restrict__ Wq, const float* __restrict__ Wk,
    float* __restrict__ wqt, float* __restrict__ wkt)
{
    const int o = blockIdx.x;
    const int d = threadIdx.x;
    if (blockIdx.y == 0) wqt[d * DD + o] = Wq[o * DD + d];
    else                 wkt[d * DD + o] = Wk[o * DD + d];
}

// ---------------------------------------------------------------------------
// prep_kT: kT4[(o>>2)*(NM*4) + n*4 + (o&3)] = k[n][o]   ([og][n][4] layout)
//   k[n][o] = sum_d mem[n][d]*Wk[o][d]  (fp32, d-ascending single-acc)
//   bias[n] = fl32(max(log(imp*0.99^age), -10))
// ---------------------------------------------------------------------------
__global__ __launch_bounds__(256) void prep_kT(
    const float* __restrict__ mem, const float* __restrict__ wkt,
    const float* __restrict__ imp, const float* __restrict__ age,
    float* __restrict__ kT4, float* __restrict__ bias)
{
    const int n = blockIdx.x;
    const int o = threadIdx.x;
    const float* mrow = mem + n * DD;
    float acc = 0.f;
    for (int d = 0; d < DD; ++d)
        acc = fmaf(mrow[d], wkt[d * DD + o], acc);
    kT4[(o >> 2) * (NM * 4) + n * 4 + (o & 3)] = acc;

    if (o == 0) {
        double eff = (double)imp[n] * pow(0.99, (double)age[n]);
        float b = (float)log(eff);
        if (!(b >= -10.0f)) b = -10.0f;
        bias[n] = b;
    }
}

// ---------------------------------------------------------------------------
// qgemm5: q = query @ Wq^T -> qout. 16 rows/wave, query streamed in 8-d
// chunks (4 KB dbuf), wqt 16 KB dbuf. Accepted basin: 8 structural variants
// all 220-242 us; ~90 us over the 109 us fp32 issue floor is the per-iter
// waitcnt/barrier drain. Chains d-ascending single-acc — bit-identical.
// ---------------------------------------------------------------------------
__global__ __launch_bounds__(256, 2) void qgemm5(
    const float* __restrict__ query,   // [M][DD]
    const float4* __restrict__ wqt4,   // [DD][NM]: wqt4[d*64+l] = WqT[d][4l..4l+3]
    float* __restrict__ qout,          // [M][DD]
    int M)
{
    __shared__ float wq_lds[2][8 * 256];    // 16 KB dbuf: [d_local][o]
    __shared__ float qc_lds[2][64 * 8];     // 4 KB dbuf: [row][d_local]

    const int t = threadIdx.x;              // 0..255
    const int l = t & 63;
    const int w = __builtin_amdgcn_readfirstlane((int)(t >> 6));  // 0..3
    const int row0 = blockIdx.x * 64;

    const int sr = t >> 2;                  // 0..63
    const int sd = (t & 3) * 2;             // 0,2,4,6
    int srow = row0 + sr; if (srow > M - 1) srow = M - 1;
    const float* qsrc = query + (size_t)srow * DD + sd;

    // stage chunk 0
    {
        const float2 qv = *reinterpret_cast<const float2*>(qsrc);
        *reinterpret_cast<float2*>(&qc_lds[0][sr * 8 + sd]) = qv;
        const float4 s0 = wqt4[t];
        const float4 s1 = wqt4[256 + t];
        reinterpret_cast<float4*>(wq_lds[0])[t]       = s0;
        reinterpret_cast<float4*>(wq_lds[0])[256 + t] = s1;
    }
    __syncthreads();

    v2f a01[16], a23[16];
#pragma unroll
    for (int rr = 0; rr < 16; ++rr) { a01[rr] = (v2f)(0.f); a23[rr] = (v2f)(0.f); }

    for (int c = 0; c < 32; ++c) {
        const int cn = (c + 1) & 31;
        const float2 nq = *reinterpret_cast<const float2*>(qsrc + cn * 8);
        const float4 n0 = wqt4[cn * 512 + t];
        const float4 n1 = wqt4[cn * 512 + 256 + t];

        {
            const float4* wb = reinterpret_cast<const float4*>(wq_lds[c & 1]);
            float4 cw[8];
#pragma unroll
            for (int i = 0; i < 8; ++i) cw[i] = wb[i * 64 + l];
            const v2x2 c0 = splitf4(cw[0]), c1 = splitf4(cw[1]);
            const v2x2 c2 = splitf4(cw[2]), c3 = splitf4(cw[3]);
            const v2x2 c4 = splitf4(cw[4]), c5 = splitf4(cw[5]);
            const v2x2 c6 = splitf4(cw[6]), c7 = splitf4(cw[7]);
            const float* qcb = &qc_lds[c & 1][(w * 16) * 8];
#pragma unroll
            for (int rr = 0; rr < 16; ++rr) {
                const float4 qqA = *reinterpret_cast<const float4*>(qcb + rr * 8);
                const float4 qqB = *reinterpret_cast<const float4*>(qcb + rr * 8 + 4);
                const v2x2 qA = splitf4(qqA);
                const v2x2 qB = splitf4(qqB);
                // d-ascending per chain (bit-identical):
                PK_FMA_SPLATLO(a01[rr], qA.lo, c0.lo);
                PK_FMA_SPLATLO(a23[rr], qA.lo, c0.hi);
                PK_FMA_SPLATHI(a01[rr], qA.lo, c1.lo);
                PK_FMA_SPLATHI(a23[rr], qA.lo, c1.hi);
                PK_FMA_SPLATLO(a01[rr], qA.hi, c2.lo);
                PK_FMA_SPLATLO(a23[rr], qA.hi, c2.hi);
                PK_FMA_SPLATHI(a01[rr], qA.hi, c3.lo);
                PK_FMA_SPLATHI(a23[rr], qA.hi, c3.hi);
                PK_FMA_SPLATLO(a01[rr], qB.lo, c4.lo);
                PK_FMA_SPLATLO(a23[rr], qB.lo, c4.hi);
                PK_FMA_SPLATHI(a01[rr], qB.lo, c5.lo);
                PK_FMA_SPLATHI(a23[rr], qB.lo, c5.hi);
                PK_FMA_SPLATLO(a01[rr], qB.hi, c6.lo);
                PK_FMA_SPLATLO(a23[rr], qB.hi, c6.hi);
                PK_FMA_SPLATHI(a01[rr], qB.hi, c7.lo);
                PK_FMA_SPLATHI(a23[rr], qB.hi, c7.hi);
            }
        }
        {
            *reinterpret_cast<float2*>(&qc_lds[(c + 1) & 1][sr * 8 + sd]) = nq;
            float4* dst = reinterpret_cast<float4*>(wq_lds[(c + 1) & 1]);
            dst[t]       = n0;
            dst[256 + t] = n1;
        }
        __syncthreads();
    }

#pragma unroll
    for (int rr = 0; rr < 16; ++rr) {
        const int grow = row0 + w * 16 + rr;
        if (grow < M) {
            float4 v; v.x = a01[rr].x; v.y = a01[rr].y; v.z = a23[rr].x; v.w = a23[rr].y;
            *reinterpret_cast<float4*>(&qout[(size_t)grow * DD + 4 * l]) = v;
        }
    }
}

// ---------------------------------------------------------------------------
// scores_b: raw biased scores -> out_attn. Byte-identical to R23/R25:
// lane = row, kT wave-uniform s_load, one swizzled b128 per og.
// ---------------------------------------------------------------------------
__global__ __launch_bounds__(512, 2) void scores_b(
    const float* __restrict__ qin,     // [M][DD] (= out_ret)
    const float4* __restrict__ kT44,   // [DD/4][NM]
    const float* __restrict__ bias,    // [NM]
    float* __restrict__ sout,          // [M][NM] (= out_attn, raw scores)
    int M)
{
    __shared__ float q_lds[64 * DD];   // 64 KB; first 16 KB reused for scores
    const int t = threadIdx.x;         // 0..511
    const int l = t & 63;
    const int w = __builtin_amdgcn_readfirstlane((int)(t >> 6));  // 0..7
    const int row0 = blockIdx.x * 64;

    // stage 64 q rows (coalesced read; swizzled write: f4-col c4 -> c4^r)
    {
        const float4* q4g = reinterpret_cast<const float4*>(qin);
#pragma unroll
        for (int i = 0; i < 8; ++i) {
            const int idx = i * 512 + t;
            const int r = idx >> 6, c4 = idx & 63;
            int gr = row0 + r; if (gr > M - 1) gr = M - 1;
            *reinterpret_cast<float4*>(&q_lds[r * DD + ((c4 ^ r) & 63) * 4]) =
                q4g[(size_t)gr * 64 + c4];
        }
    }
    __syncthreads();

    // lane l = row l; wave w owns n in [8w, 8w+8)
    const int nb = w * 8;
    float sc[8];
#pragma unroll
    for (int j = 0; j < 8; ++j) sc[j] = 0.f;

    for (int og = 0; og < DD / 4; ++og) {
        const float4 q4 = *reinterpret_cast<const float4*>(
            &q_lds[l * DD + (((og ^ l) & 63) << 2)]);     // per-lane, conflict-free
        const float4* ktp = kT44 + og * NM + nb;          // wave-uniform -> s_load
#pragma unroll
        for (int j = 0; j < 8; ++j) {
            const float4 kt = ktp[j];
            float v = sc[j];
            v = fmaf(q4.x, kt.x, v);                      // o-ascending chain
            v = fmaf(q4.y, kt.y, v);
            v = fmaf(q4.z, kt.z, v);
            v = fmaf(q4.w, kt.w, v);
            sc[j] = v;
        }
    }
    __syncthreads();   // all q reads done -> reuse LDS for scores

    // rotated score tile: row l, col c stored at (c+l)&63 (conflict-free)
    float* s_tmp = q_lds;              // [64][64] = 16 KB
#pragma unroll
    for (int j = 0; j < 8; ++j)
        s_tmp[l * NM + ((nb + j + l) & 63)] = sc[j] * 0.0625f + bias[nb + j];
    __syncthreads();

    // coalesced stores
#pragma unroll
    for (int i = 0; i < 8; ++i) {
        const int idx = i * 512 + t;
        const int r = idx >> 6, n = idx & 63;
        const int grow = row0 + r;
        if (grow < M) sout[(size_t)grow * NM + n] = s_tmp[r * NM + ((n + r) & 63)];
    }
}

// ---------------------------------------------------------------------------
// fin3: raw scores (out_attn) -> topk (thread-per-row, 128 rows) -> final
// attn (overwrite out_attn, block-local) + retrieved (write out_ret fresh).
// Byte-identical to R19/R23/R25's fin3.
// ---------------------------------------------------------------------------
#define FR 128    // rows per fin3 block
__global__ __launch_bounds__(256, 2) void fin3(
    const float* __restrict__ mem,     // [NM][DD]
    const int* __restrict__ topk_p,
    float* __restrict__ out_ret,       // [M][DD]
    float* __restrict__ out_attn,      // [M][NM] (raw scores in, attn out)
    int M)
{
    __shared__ float s_lds[FR * NM];   // 32 KB rotated scores
    __shared__ int   sel_i[FR * 16];   // 8 KB
    __shared__ float sel_w[FR * 16];   // 8 KB

    const int t = threadIdx.x;
    const int l = t & 63;
    const int w = __builtin_amdgcn_readfirstlane((int)(t >> 6));  // 0..3
    const int row0 = blockIdx.x * FR;
    const int k = *topk_p;

    // stage scores (coalesced read, rotated scatter: col c at (c+r)&63)
    {
#pragma unroll
        for (int i = 0; i < (FR * NM / 4) / 256; ++i) {    // 8 iters
            const int idx = i * 256 + t;                   // float4 index
            const int r = idx >> 4, c4 = idx & 15;
            int gr = row0 + r; if (gr > M - 1) gr = M - 1;
            const float4 v = *reinterpret_cast<const float4*>(
                &out_attn[(size_t)gr * NM + c4 * 4]);
            s_lds[r * NM + ((c4 * 4 + 0 + r) & 63)] = v.x;
            s_lds[r * NM + ((c4 * 4 + 1 + r) & 63)] = v.y;
            s_lds[r * NM + ((c4 * 4 + 2 + r) & 63)] = v.z;
            s_lds[r * NM + ((c4 * 4 + 3 + r) & 63)] = v.w;
        }
    }
    __syncthreads();

    // ---- per-row top-k: thread t handles row t (t < FR)
    if (t < FR) {
        const int r = t;
        float sv[NM];
#pragma unroll
        for (int n = 0; n < NM; ++n) sv[n] = s_lds[r * NM + ((n + r) & 63)];

        if (k < NM) {
            const int kk = k < 16 ? k : 16;   // dataset: k = 8
            u64 taken = 0ull;
            float mmax = 0.f, Z = 0.f;
            for (int i = 0; i < kk; ++i) {
                float m = -1.0e30f;
                int idx = 0;
#pragma unroll
                for (int n = 0; n < NM; ++n) {
                    const bool avail  = ((taken >> n) & 1ull) == 0ull;
                    const bool better = avail && (sv[n] > m);  // strict >: lowest idx ties
                    m   = better ? sv[n] : m;
                    idx = better ? n : idx;
                }
                taken |= (1ull << idx);
                if (i == 0) mmax = m;
                const float wv = expf(m - mmax);
                Z += wv;
                sel_i[r * 16 + i] = idx;
                sel_w[r * 16 + i] = wv;
            }
#pragma unroll
            for (int n = 0; n < NM; ++n) s_lds[r * NM + ((n + r) & 63)] = 0.f;
            for (int i = 0; i < kk; ++i) {
                const float wz = sel_w[r * 16 + i] / Z;
                sel_w[r * 16 + i] = wz;
                s_lds[r * NM + ((sel_i[r * 16 + i] + r) & 63)] = wz;
            }
        } else {
            float m = -1.0e30f;
#pragma unroll
            for (int n = 0; n < NM; ++n) m = sv[n] > m ? sv[n] : m;
            float Z = 0.f;
#pragma unroll
            for (int n = 0; n < NM; ++n) Z += expf(sv[n] - m);
#pragma unroll
            for (int n = 0; n < NM; ++n) s_lds[r * NM + ((n + r) & 63)] = expf(sv[n] - m) / Z;
        }
    }
    __syncthreads();

    // ---- attn stores (coalesced)
#pragma unroll
    for (int i = 0; i < (FR * NM) / 256; ++i) {    // 32 iters
        const int idx = i * 256 + t;
        const int r = idx >> 6, n = idx & 63;
        const int grow = row0 + r;
        if (grow < M) out_attn[(size_t)grow * NM + n] = s_lds[r * NM + ((n + r) & 63)];
    }

    // ---- retrieved (PV): wave w rows [32w, 32w+32); lane l = d-quad
    {
        const float4* mem4 = reinterpret_cast<const float4*>(mem);   // [NM][64]
        const int kk = k < 16 ? k : 16;
#pragma unroll 1
        for (int rr = 0; rr < FR / 4; ++rr) {
            const int r    = w * (FR / 4) + rr;
            const int grow = row0 + r;
            if (grow >= M) continue;
            float4 acc; acc.x = 0.f; acc.y = 0.f; acc.z = 0.f; acc.w = 0.f;
            if (k < NM) {
                for (int i = 0; i < kk; ++i) {
                    const int   mi = sel_i[r * 16 + i];      // uniform ds
                    const float wz = sel_w[r * 16 + i];
                    const float4 mv = mem4[mi * 64 + l];     // coalesced, L1-hot
                    acc.x = fmaf(wz, mv.x, acc.x);           // rank-ascending chain
                    acc.y = fmaf(wz, mv.y, acc.y);
                    acc.z = fmaf(wz, mv.z, acc.z);
                    acc.w = fmaf(wz, mv.w, acc.w);
                }
            } else {
                for (int n = 0; n < NM; ++n) {
                    const float wz = s_lds[r * NM + ((n + r) & 63)];
                    const float4 mv = mem4[n * 64 + l];
                    acc.x = fmaf(wz, mv.x, acc.x);           // n-ascending chain
                    acc.y = fmaf(wz, mv.y, acc.y);
                    acc.z = fmaf(wz, mv.z, acc.z);
                    acc.w = fmaf(wz, mv.w, acc.w);
                }
            }
            *reinterpret_cast<float4*>(&out_ret[(size_t)grow * DD + 4 * l]) = acc;
        }
    }
}

// ---------------------------------------------------------------------------
extern "C" void kernel_launch(void* const* d_in, const int* in_sizes, int n_in,
                              void* d_out, int out_size, void* d_ws, size_t ws_size,
                              hipStream_t stream) {
    const float* query      = (const float*)d_in[0];
    const float* memory     = (const float*)d_in[1];
    const float* importance = (const float*)d_in[2];
    const float* age        = (const float*)d_in[3];
    const float* Wq         = (const float*)d_in[4];
    const float* Wk         = (const float*)d_in[5];
    const int*   topk       = (const int*)d_in[6];

    const int M = in_sizes[0] / DD;   // B*S = 131072

    float* kT4  = (float*)d_ws;                      // 64 KB [og][n][4]
    float* bias = kT4 + (size_t)DD * NM;             // [NM]
    float* wqt  = bias + 64;                         // [DD][DD] = 256 KB
    float* wkt  = wqt + (size_t)DD * DD;             // [DD][DD] = 256 KB

    hipLaunchKernelGGL(prep_tr, dim3(DD, 2), dim3(DD), 0, stream,
                       Wq, Wk, wqt, wkt);
    hipLaunchKernelGGL(prep_kT, dim3(NM), dim3(DD), 0, stream,
                       memory, wkt, importance, age, kT4, bias);

    float* out_ret  = (float*)d_out;
    float* out_attn = out_ret + (size_t)M * DD;

    // q staged through out_ret; raw scores through out_attn; fin3 reads its
    // own rows of both before overwriting with final outputs.
    hipLaunchKernelGGL(qgemm5, dim3((M + 63) / 64), dim3(256), 0, stream,
                       query, (const float4*)wqt, out_ret, M);
    hipLaunchKernelGGL(scores_b, dim3((M + 63) / 64), dim3(512), 0, stream,
                       out_ret, (const float4*)kT4, bias, out_attn, M);
    hipLaunchKernelGGL(fin3, dim3((M + FR - 1) / FR), dim3(256), 0, stream,
                       memory, topk, out_ret, out_attn, M);
}